// Round 3
// baseline (1473.133 us; speedup 1.0000x reference)
//
#include <hip/hip_runtime.h>
#include <stdint.h>

constexpr int B = 512, S = 1024, IN = 32, H = 128;
constexpr int KTOT = IN + H;   // 160
constexpr int KSL = KTOT / 4;  // 40 k per j-slice
constexpr int KP = KSL / 2;    // 20 half2 pairs per gate-row

typedef uint32_t u32;

template <int CTRL>
__device__ __forceinline__ float dpp_qp(float v) {
  return __int_as_float(__builtin_amdgcn_update_dpp(
      0, __float_as_int(v), CTRL, 0xF, 0xF, true));
}
// D = a.h0*b.h0 + a.h1*b.h1 + D  (fp16 inputs, fp32 accumulate)
__device__ __forceinline__ void dot2(float& c, u32 a, u32 b) {
  asm("v_dot2_f32_f16 %0, %1, %2, %0" : "+v"(c) : "v"(a), "v"(b));
}
__device__ __forceinline__ float sigm(float v) {
  float e = __builtin_amdgcn_exp2f(-1.4426950408889634f * v);
  return __builtin_amdgcn_rcpf(1.0f + e);
}
__device__ __forceinline__ float tanh_(float v) {
  float e = __builtin_amdgcn_exp2f(-2.8853900817779268f * v);
  return 2.0f * __builtin_amdgcn_rcpf(1.0f + e) - 1.0f;
}

__global__ __launch_bounds__(512, 2)
void lstm_fused(const float* __restrict__ x, const float* __restrict__ Wih,
                const float* __restrict__ Whh, const float* __restrict__ bih,
                const float* __restrict__ bhh, const float* __restrict__ Wlin,
                const float* __restrict__ blin, float* __restrict__ out) {
  // ping-pong [buf][batch][k] fp16 state: x_t(32) | h(128). 320B per row.
  __shared__ alignas(16) _Float16 hx[2][2][KTOT];
  __shared__ float red[2 * H];

  const int tid = threadIdx.x;
  const int g = tid >> 2;  // hidden unit 0..127
  const int j = tid & 3;   // k-slice 0..3
  const int b0 = blockIdx.x * 2;

  // ---- weights -> packed half2 registers: 4 gates x 20 pairs = 80 VGPRs ----
  u32 w[4][KP];
#pragma unroll
  for (int c = 0; c < 4; ++c) {
    const int n = c * H + g;
#pragma unroll
    for (int p = 0; p < KP; ++p) {
      const int k0 = KSL * j + 2 * p;
      const int k1 = k0 + 1;
      const float f0 = (k0 < IN) ? Wih[n * IN + k0] : Whh[n * H + (k0 - IN)];
      const float f1 = (k1 < IN) ? Wih[n * IN + k1] : Whh[n * H + (k1 - IN)];
      union { _Float16 h[2]; u32 u; } cv;
      cv.h[0] = (_Float16)f0;
      cv.h[1] = (_Float16)f1;
      w[c][p] = cv.u;
    }
  }
  // pin weights into VGPRs (defeat load rematerialization — round2's VGPR=112 bug)
#pragma unroll
  for (int c = 0; c < 4; ++c)
#pragma unroll
    for (int p = 0; p < KP; ++p) asm volatile("" : "+v"(w[c][p]));

  float bias[4];
#pragma unroll
  for (int c = 0; c < 4; ++c) bias[c] = bih[c * H + g] + bhh[c * H + g];

  // ---- init buf0: zero h, stage x for s=0 ----
  if (tid < 2 * KTOT) ((_Float16*)hx)[tid] = (_Float16)0.0f;
  __syncthreads();
  if (tid < 2 * IN) {
    const int b = tid >> 5, k = tid & 31;
    hx[0][b][k] = (_Float16)x[(size_t)(b0 + b) * (S * IN) + k];
  }
  __syncthreads();

  float cc = 0.f;  // cell state for (g, batch=j&1); lanes j and j+2 duplicate
  float oa = 0.f;  // fused output-linear accumulator (valid on j<2)
  const int xb = g >> 5, xk = g & 31;
  const int bb = j & 1;

  for (int s = 0; s < S; ++s) {
    const int p = s & 1, np = p ^ 1;
    // prefetch W_lin slice (this step) and x (next step) early
    float wl = 0.f, xn = 0.f;
    if (j < 2) wl = Wlin[s * H + g];
    const bool xload = (j == 2) && (g < 64) && (s + 1 < S);
    if (xload) xn = x[(size_t)(b0 + xb) * (S * IN) + (s + 1) * IN + xk];

    // ---- gate GEMM slice: 160 v_dot2 (2 MACs each) ----
    float acc[4][2];
#pragma unroll
    for (int c = 0; c < 4; ++c) { acc[c][0] = 0.f; acc[c][1] = 0.f; }
#pragma unroll
    for (int b = 0; b < 2; ++b) {
      const uint4* pp = reinterpret_cast<const uint4*>(&hx[p][b][KSL * j]);
#pragma unroll
      for (int q = 0; q < 5; ++q) {
        const uint4 v = pp[q];
        const u32 e[4] = {v.x, v.y, v.z, v.w};
#pragma unroll
        for (int u = 0; u < 4; ++u)
#pragma unroll
          for (int c = 0; c < 4; ++c) dot2(acc[c][b], e[u], w[c][4 * q + u]);
      }
    }
    // ---- quad butterfly reduce over k-slices (VALU DPP) ----
#pragma unroll
    for (int c = 0; c < 4; ++c)
#pragma unroll
      for (int b = 0; b < 2; ++b) {
        float v = acc[c][b];
        v += dpp_qp<0xB1>(v);  // xor 1
        v += dpp_qp<0x4E>(v);  // xor 2
        acc[c][b] = v;
      }
    // ---- activations: all lanes, pair-redundant (lane handles batch j&1) ----
    const float gi = sigm(acc[0][bb] + bias[0]);
    const float gf = sigm(acc[1][bb] + bias[1]);
    const float gg = tanh_(acc[2][bb] + bias[2]);
    const float go = sigm(acc[3][bb] + bias[3]);
    cc = gf * cc + gi * gg;
    const float h = go * tanh_(cc);
    if (j < 2) {
      hx[np][bb][IN + g] = (_Float16)h;  // h for step s+1
      oa += h * wl;
    } else if (xload) {
      hx[np][xb][xk] = (_Float16)xn;     // x for step s+1
    }
    __syncthreads();  // single barrier: hx[np] ready, hx[p] free
  }

  // ---- final reduce of fused linear ----
  if (j < 2) red[j * H + g] = oa;
  __syncthreads();
  if (tid < 2) {
    float sum = blin[0];
    for (int k = 0; k < H; ++k) sum += red[tid * H + k];
    out[b0 + tid] = sum;
  }
}

extern "C" void kernel_launch(void* const* d_in, const int* in_sizes, int n_in,
                              void* d_out, int out_size, void* d_ws, size_t ws_size,
                              hipStream_t stream) {
  const float* x    = (const float*)d_in[0];
  const float* Wih  = (const float*)d_in[1];
  const float* Whh  = (const float*)d_in[2];
  const float* bih  = (const float*)d_in[3];
  const float* bhh  = (const float*)d_in[4];
  const float* Wlin = (const float*)d_in[5];
  const float* blin = (const float*)d_in[6];
  float* outp = (float*)d_out;
  hipLaunchKernelGGL(lstm_fused, dim3(B / 2), dim3(512), 0, stream,
                     x, Wih, Whh, bih, bhh, Wlin, blin, outp);
}

// Round 4
// 1264.434 us; speedup vs baseline: 1.1651x; 1.1651x over previous
//
#include <hip/hip_runtime.h>
#include <stdint.h>

constexpr int B = 512, S = 1024, IN = 32, H = 128;
constexpr int KTOT = IN + H;    // 160
constexpr int NJ = 4;           // k-slices (wave-uniform)
constexpr int KSL = KTOT / NJ;  // 40 k per slice
constexpr int KP = KSL / 2;     // 20 half2 pairs

typedef uint32_t u32;

// D = a.h0*b.h0 + a.h1*b.h1 + D  (fp16 inputs, fp32 accumulate)
__device__ __forceinline__ void dot2(float& c, u32 a, u32 b) {
  asm("v_dot2_f32_f16 %0, %1, %2, %0" : "+v"(c) : "v"(a), "v"(b));
}
__device__ __forceinline__ float sigm(float v) {
  float e = __builtin_amdgcn_exp2f(-1.4426950408889634f * v);
  return __builtin_amdgcn_rcpf(1.0f + e);
}
__device__ __forceinline__ float tanh_(float v) {
  float e = __builtin_amdgcn_exp2f(-2.8853900817779268f * v);
  return 2.0f * __builtin_amdgcn_rcpf(1.0f + e) - 1.0f;
}

__global__ __launch_bounds__(512, 4)
void lstm_fused(const float* __restrict__ x, const float* __restrict__ Wih,
                const float* __restrict__ Whh, const float* __restrict__ bih,
                const float* __restrict__ bhh, const float* __restrict__ Wlin,
                const float* __restrict__ blin, float* __restrict__ out) {
  __shared__ alignas(16) _Float16 hx[2][KTOT];  // ping-pong [x(32)|h(128)], fp16
  __shared__ alignas(16) float red[NJ][H][4];   // per-slice partials [j][g][gate]
  __shared__ float redf[H];

  const int tid = threadIdx.x;
  const int lane = tid & 63;
  const int w = tid >> 6;             // wave 0..7
  const int j = w >> 1;               // k-slice, wave-uniform
  const int g = (w & 1) * 64 + lane;  // gate-row this thread dots for
  const int b = blockIdx.x;           // one batch row per block
  const int par = b & 1;
  const int aw0 = par, aw1 = 6 + par; // activation waves (stagger SIMDs by parity)
  const bool isact = (w == aw0) || (w == aw1);
  const int ga = (w == aw0) ? lane : 64 + lane;  // act-wave's gate-row
  const int xw = 2 + par;             // x-prefetch wave

  // ---- weights -> packed half2 regs: 4 gates x 20 pairs = 80 VGPRs ----
  u32 wreg[4][KP];
#pragma unroll
  for (int c = 0; c < 4; ++c) {
    const int n = c * H + g;
#pragma unroll
    for (int pq = 0; pq < KP; ++pq) {
      const int k0 = KSL * j + 2 * pq, k1 = k0 + 1;
      const float f0 = (k0 < IN) ? Wih[n * IN + k0] : Whh[n * H + (k0 - IN)];
      const float f1 = (k1 < IN) ? Wih[n * IN + k1] : Whh[n * H + (k1 - IN)];
      union { _Float16 h[2]; u32 u; } cv;
      cv.h[0] = (_Float16)f0;
      cv.h[1] = (_Float16)f1;
      wreg[c][pq] = cv.u;
    }
  }
  // pin into VGPRs (defeat load rematerialization)
#pragma unroll
  for (int c = 0; c < 4; ++c)
#pragma unroll
    for (int pq = 0; pq < KP; ++pq) asm volatile("" : "+v"(wreg[c][pq]));

  float bias_a[4] = {0.f, 0.f, 0.f, 0.f};
  if (isact) {
#pragma unroll
    for (int c = 0; c < 4; ++c) bias_a[c] = bih[c * H + ga] + bhh[c * H + ga];
  }

  // ---- init: hx[0] = (x_0 | zeros); hx[1] zeroed for safety ----
  const size_t xbase = (size_t)b * S * IN;
  if (tid < KTOT) {
    hx[0][tid] = (tid < IN) ? (_Float16)x[xbase + tid] : (_Float16)0.0f;
    hx[1][tid] = (_Float16)0.0f;
  }
  __syncthreads();

  float cc = 0.f, oa = 0.f;

  for (int s = 0; s < S; ++s) {
    const int p = s & 1, np = p ^ 1;
    // early global loads (latency hidden under dots)
    float wl = 0.f, xn = 0.f;
    if (isact) wl = Wlin[s * H + ga];
    const bool xload = (w == xw) && (lane < IN) && (s + 1 < S);
    if (xload) xn = x[xbase + (s + 1) * IN + lane];

    // ---- dots: wave-broadcast LDS reads of this wave's k-slice ----
    const uint4* pp =
        (const uint4*)((const char*)&hx[p][0] + j * (KSL * 2));
    float acc[4] = {0.f, 0.f, 0.f, 0.f};
#pragma unroll
    for (int q = 0; q < 5; ++q) {
      const uint4 v = pp[q];
      const u32 e[4] = {v.x, v.y, v.z, v.w};
#pragma unroll
      for (int u = 0; u < 4; ++u)
#pragma unroll
        for (int c = 0; c < 4; ++c) dot2(acc[c], e[u], wreg[c][4 * q + u]);
    }
    *(float4*)&red[j][g][0] = make_float4(acc[0], acc[1], acc[2], acc[3]);
    __syncthreads();  // A: partials visible

    if (isact) {
      const float4 r0 = *(const float4*)&red[0][ga][0];
      const float4 r1 = *(const float4*)&red[1][ga][0];
      const float4 r2 = *(const float4*)&red[2][ga][0];
      const float4 r3 = *(const float4*)&red[3][ga][0];
      const float gi = sigm(r0.x + r1.x + r2.x + r3.x + bias_a[0]);
      const float gf = sigm(r0.y + r1.y + r2.y + r3.y + bias_a[1]);
      const float gg = tanh_(r0.z + r1.z + r2.z + r3.z + bias_a[2]);
      const float go = sigm(r0.w + r1.w + r2.w + r3.w + bias_a[3]);
      cc = gf * cc + gi * gg;
      const float h = go * tanh_(cc);
      hx[np][IN + ga] = (_Float16)h;  // h_s for step s+1
      oa += h * wl;                   // fused output linear
    } else if (xload) {
      hx[np][lane] = (_Float16)xn;    // x_{s+1}
    }
    __syncthreads();  // B: hx[np] complete
  }

  // ---- final reduce of fused linear ----
  if (isact) redf[ga] = oa;
  __syncthreads();
  if (tid == 0) {
    float sum = blin[0];
    for (int k = 0; k < H; ++k) sum += redf[k];
    out[b] = sum;
  }
}

extern "C" void kernel_launch(void* const* d_in, const int* in_sizes, int n_in,
                              void* d_out, int out_size, void* d_ws, size_t ws_size,
                              hipStream_t stream) {
  const float* x    = (const float*)d_in[0];
  const float* Wih  = (const float*)d_in[1];
  const float* Whh  = (const float*)d_in[2];
  const float* bih  = (const float*)d_in[3];
  const float* bhh  = (const float*)d_in[4];
  const float* Wlin = (const float*)d_in[5];
  const float* blin = (const float*)d_in[6];
  float* outp = (float*)d_out;
  hipLaunchKernelGGL(lstm_fused, dim3(B), dim3(512), 0, stream,
                     x, Wih, Whh, bih, bhh, Wlin, blin, outp);
}